// Round 2
// baseline (239.018 us; speedup 1.0000x reference)
//
#include <hip/hip_runtime.h>
#include <hip/hip_bf16.h>
#include <cstdint>

// CTC forward loss (keras ctc_batch_cost semantics), B=64 T=1024 L=128 V=512.
// Probability-domain scaled forward algorithm:
//   alpha_new[s] = (alpha[s] + alpha[s-1] + allow_skip[s]*alpha[s-2]) * (p_t[ext[s]] + EPS)
// with power-of-2 renormalization every 4 steps (exact exponent bookkeeping).
// One wave per batch row; lane j owns states 4j..4j+3 (lane 63 also state 256).

#define CTC_B 64
#define CTC_T 1024
#define CTC_L 128
#define CTC_V 512
#define BLANK (CTC_V - 1)
#define EPSF 1e-7f
#define DPF 8   // prefetch depth (time steps)

__global__ __launch_bounds__(64, 1)
void ctc_fwd_kernel(const int* __restrict__ y_true,
                    const float* __restrict__ y_pred,
                    float* __restrict__ out) {
    const int b = blockIdx.x;
    const int j = threadIdx.x;  // lane 0..63
    const float* __restrict__ yb = y_pred + (size_t)b * CTC_T * CTC_V;

    // labels owned by this lane: states 4j+1 -> lab[2j], 4j+3 -> lab[2j+1]
    const int labA = y_true[b * CTC_L + 2 * j];
    const int labB = y_true[b * CTC_L + 2 * j + 1];
    const int labPrev = __shfl_up(labB, 1);  // lab[2j-1] (junk at lane 0, unused)

    // skip-transition masks (blank states never skip)
    const float msk1 = (labA != labPrev) ? 1.0f : 0.0f;  // state 4j+1 (lane0: pm1==0 anyway)
    const float msk3 = (labB != labA) ? 1.0f : 0.0f;     // state 4j+3

    // t = 0 init: only states 0 (blank) and 1 (first label) alive
    float a0 = 0.0f, a1 = 0.0f, a2 = 0.0f, a3 = 0.0f, a4 = 0.0f;
    {
        const float pb0 = yb[BLANK] + EPSF;
        const float pl0 = yb[labA] + EPSF;  // lane 0's labA == lab[0]
        if (j == 0) { a0 = pb0; a1 = pl0; }
    }

    int Eacc = 0;  // accumulated power-of-2 exponent from renormalization

    // prefetch slots: slot k holds row (group_base + k)'s three probs
    float pfb[DPF], pfa[DPF], pfc[DPF];
#pragma unroll
    for (int k = 0; k < DPF; ++k) {
        const float* rw = yb + (size_t)(1 + k) * CTC_V;
        pfb[k] = rw[BLANK];
        pfa[k] = rw[labA];
        pfc[k] = rw[labB];
    }

#define RENORM do {                                                        \
        float m = fmaxf(fmaxf(fmaxf(a0, a1), fmaxf(a2, a3)), a4);          \
        m = fmaxf(m, __shfl_xor(m, 1));                                    \
        m = fmaxf(m, __shfl_xor(m, 2));                                    \
        m = fmaxf(m, __shfl_xor(m, 4));                                    \
        m = fmaxf(m, __shfl_xor(m, 8));                                    \
        m = fmaxf(m, __shfl_xor(m, 16));                                   \
        m = fmaxf(m, __shfl_xor(m, 32));                                   \
        int e = (int)((__float_as_uint(m) >> 23) & 255u) - 127;            \
        float sc = __uint_as_float((unsigned)(127 - e) << 23);             \
        a0 *= sc; a1 *= sc; a2 *= sc; a3 *= sc; a4 *= sc;                  \
        Eacc += e;                                                         \
    } while (0)

    // One time step. kk is a compile-time literal (slot index stays static).
    // Renorm when global step t = tb+kk satisfies t % 4 == 0; tb ≡ 1 (mod 8)
    // so that is kk == 3 or kk == 7.
#define STEP(kk, DO_PF) do {                                               \
        const float pb = pfb[kk] + EPSF;                                   \
        const float pA = pfa[kk] + EPSF;                                   \
        const float pB = pfc[kk] + EPSF;                                   \
        float pm1 = __shfl_up(a3, 1);                                      \
        pm1 = (j == 0) ? 0.0f : pm1;                                       \
        const float n0 = (a0 + pm1) * pb;                                  \
        const float n1 = fmaf(msk1, pm1, a0 + a1) * pA;                    \
        const float n2 = (a1 + a2) * pb;                                   \
        const float n3 = fmaf(msk3, a1, a2 + a3) * pB;                     \
        const float n4 = (a3 + a4) * pb;                                   \
        a0 = n0; a1 = n1; a2 = n2; a3 = n3; a4 = n4;                       \
        if (DO_PF) {                                                       \
            const int tn = tb + (kk) + DPF;                                \
            if (tn < CTC_T) {                                              \
                const float* rw = yb + (size_t)tn * CTC_V;                 \
                pfb[kk] = rw[BLANK];                                       \
                pfa[kk] = rw[labA];                                        \
                pfc[kk] = rw[labB];                                        \
            }                                                              \
        }                                                                  \
        if ((((kk) + 1) & 3) == 0) { RENORM; }                             \
    } while (0)

    int tb = 1;
    for (; tb + DPF <= CTC_T; tb += DPF) {
        STEP(0, true); STEP(1, true); STEP(2, true); STEP(3, true);
        STEP(4, true); STEP(5, true); STEP(6, true); STEP(7, true);
    }
    // tail: tb == 1017, steps t = 1017..1023 (7 steps), slots 0..6
    STEP(0, false); STEP(1, false); STEP(2, false);
    STEP(3, false); STEP(4, false); STEP(5, false); STEP(6, false);

#undef STEP
#undef RENORM

    // final: logaddexp(alpha[S-1], alpha[S-2]) -> log(a4 + a3) on lane 63
    if (j == 63) {
        const float sum = a3 + a4;
        const float logp = logf(sum) + (float)Eacc * 0.69314718055994530942f;
        out[b] = -logp;
    }
}

extern "C" void kernel_launch(void* const* d_in, const int* in_sizes, int n_in,
                              void* d_out, int out_size, void* d_ws, size_t ws_size,
                              hipStream_t stream) {
    const int* y_true = (const int*)d_in[0];     // [B, L] int32
    const float* y_pred = (const float*)d_in[1]; // [B, T, V] float32
    float* out = (float*)d_out;                  // [B, 1] float32

    ctc_fwd_kernel<<<CTC_B, 64, 0, stream>>>(y_true, y_pred, out);
}

// Round 3
// 103.022 us; speedup vs baseline: 2.3201x; 2.3201x over previous
//
#include <hip/hip_runtime.h>
#include <hip/hip_bf16.h>
#include <cstdint>

// CTC forward loss (keras ctc_batch_cost), B=64 T=1024 L=128 V=512.
// Probability-domain scaled forward algorithm with producer-consumer waves:
//   wave 0:  sequential scan, states 4j..4j+3 (+256 on lane 63) per lane
//   waves 1-3: gather p[t][ext_labels] into LDS ring via global_load_lds
// Renorm every 4 steps by power-of-2 (exact), scale application deferred one
// period so the cross-lane max reduce is off the critical dependency chain.

#define CTC_B 64
#define CTC_T 1024
#define CTC_L 128
#define CTC_V 512
#define BLANK (CTC_V - 1)
#define EPSF 1e-7f
#define LN2F 0.69314718055994530942f

#define CHUNK 32              // time steps per chunk
#define NCH   (CTC_T / CHUNK) // 32 chunks
#define SLOTW 192             // floats per step slot: [0..127]=label probs, [128..191]=blank copies
#define REG   (CHUNK + 4)     // slots per ring region (+4 pad for lookahead reads)

__device__ __forceinline__ void gld_lds(const float* g, float* l) {
    // global gather (per-lane addr) -> LDS at uniform base + lane*4
    __builtin_amdgcn_global_load_lds(
        (const __attribute__((address_space(1))) unsigned int*)g,
        (__attribute__((address_space(3))) unsigned int*)l,
        4, 0, 0);
}

__global__ __launch_bounds__(256, 1)
void ctc_fwd_pc(const int* __restrict__ y_true,
                const float* __restrict__ y_pred,
                float* __restrict__ out) {
    __shared__ __align__(16) float ring[2 * REG * SLOTW];  // 55296 B

    const int b = blockIdx.x;
    const int tid = threadIdx.x;
    const int wave = tid >> 6;
    const int lane = tid & 63;
    const float* __restrict__ yb = y_pred + (size_t)b * CTC_T * CTC_V;

    // ---- producer lane labels: gather-1 word[lane]=p[lab[lane]], gather-2 word[64+lane]=p[lab[64+lane]]
    const int labLo = y_true[b * CTC_L + lane];
    const int labHi = y_true[b * CTC_L + 64 + lane];

    // ---- consumer lane labels: states 4j+1 -> lab[2j], 4j+3 -> lab[2j+1]
    const int labA = y_true[b * CTC_L + 2 * lane];
    const int labB = y_true[b * CTC_L + 2 * lane + 1];
    const int labPrev = __shfl_up(labB, 1);
    const float msk1 = (labA != labPrev) ? 1.0f : 0.0f;
    const float msk3 = (labB != labA) ? 1.0f : 0.0f;

    // consumer scan state
    float a0 = 0.0f, a1 = 0.0f, a2 = 0.0f, a3 = 0.0f, a4 = 0.0f;
    float curScale = 1.0f;
    int curE = 0;
    int Eacc = 0;

#define FILL(c_) do {                                                      \
        const int base_ = ((c_) & 1) * REG;                                \
        const int t0_ = (c_) * CHUNK;                                      \
        for (int l_ = wave - 1; l_ < CHUNK; l_ += 3) {                     \
            const float* row_ = yb + (size_t)(t0_ + l_) * CTC_V;           \
            float* slot_ = &ring[(base_ + l_) * SLOTW];                    \
            gld_lds(row_ + labLo, slot_);                                  \
            gld_lds(row_ + labHi, slot_ + 64);                             \
            gld_lds(row_ + BLANK, slot_ + 128);                            \
        }                                                                  \
    } while (0)

#define LD2(s_) (*(const float2*)&ring[(s_) * SLOTW + 2 * lane])
#define LDB(s_) (ring[(s_) * SLOTW + 128])

#define DOSTEP(qv, bv, RN) do {                                            \
        const float pb_ = (bv) + EPSF;                                     \
        const float pA_ = (qv).x + EPSF;                                   \
        const float pB_ = (qv).y + EPSF;                                   \
        float pm1 = __shfl_up(a3, 1);                                      \
        pm1 = (lane == 0) ? 0.0f : pm1;                                    \
        const float n0 = (a0 + pm1) * pb_;                                 \
        const float n1 = fmaf(msk1, pm1, a0 + a1) * pA_;                   \
        const float n2 = (a1 + a2) * pb_;                                  \
        const float n3 = fmaf(msk3, a1, a2 + a3) * pB_;                    \
        const float n4 = (a3 + a4) * pb_;                                  \
        a0 = n0; a1 = n1; a2 = n2; a3 = n3; a4 = n4;                       \
        if (RN) {                                                          \
            a0 *= curScale; a1 *= curScale; a2 *= curScale;                \
            a3 *= curScale; a4 *= curScale;                                \
            Eacc += curE;                                                  \
            float m_ = fmaxf(fmaxf(fmaxf(a0, a1), fmaxf(a2, a3)), a4);     \
            m_ = fmaxf(m_, __shfl_xor(m_, 1));                             \
            m_ = fmaxf(m_, __shfl_xor(m_, 2));                             \
            m_ = fmaxf(m_, __shfl_xor(m_, 4));                             \
            m_ = fmaxf(m_, __shfl_xor(m_, 8));                             \
            m_ = fmaxf(m_, __shfl_xor(m_, 16));                            \
            m_ = fmaxf(m_, __shfl_xor(m_, 32));                            \
            const int e_ = (int)((__float_as_uint(m_) >> 23) & 255u) - 127;\
            curE = e_;                                                     \
            curScale = __uint_as_float((unsigned)(127 - e_) << 23);        \
        }                                                                  \
    } while (0)

    // prologue: fill chunk 0
    if (wave != 0) FILL(0);
    __syncthreads();

    for (int c = 0; c < NCH; ++c) {
        if (wave == 0) {
            // ---------------- consumer: process chunk c ----------------
            const int sb = (c & 1) * REG;
            int l;
            if (c == 0) {
                // t=0 init: states 0 (blank) and 1 (lab[0]) only
                const float pb0 = ring[128] + EPSF;      // slot 0, blank
                const float pl0 = ring[0] + EPSF;        // slot 0, word 0 = p[lab[0]]
                if (lane == 0) { a0 = pb0; a1 = pl0; }
                l = 1;
            } else {
                l = 0;
            }
            float2 q0 = LD2(sb + l),     q1 = LD2(sb + l + 1);
            float2 q2 = LD2(sb + l + 2), q3 = LD2(sb + l + 3);
            float  b0 = LDB(sb + l),     b1 = LDB(sb + l + 1);
            float  b2 = LDB(sb + l + 2), b3 = LDB(sb + l + 3);
            if (c == 0) {
                // steps t = 1..28 in groups of 4; renorm at t%4==0 -> 4th position
                for (; l + 4 <= CHUNK; l += 4) {
                    DOSTEP(q0, b0, 0); q0 = LD2(sb + l + 4); b0 = LDB(sb + l + 4);
                    DOSTEP(q1, b1, 0); q1 = LD2(sb + l + 5); b1 = LDB(sb + l + 5);
                    DOSTEP(q2, b2, 0); q2 = LD2(sb + l + 6); b2 = LDB(sb + l + 6);
                    DOSTEP(q3, b3, 1); q3 = LD2(sb + l + 7); b3 = LDB(sb + l + 7);
                }
                // remainder: t = 29,30,31 (no renorm)
                DOSTEP(q0, b0, 0); DOSTEP(q1, b1, 0); DOSTEP(q2, b2, 0);
            } else {
                // steps t = 32c..32c+31; renorm at position 0 (t%4==0)
                for (; l + 4 <= CHUNK; l += 4) {
                    DOSTEP(q0, b0, 1); q0 = LD2(sb + l + 4); b0 = LDB(sb + l + 4);
                    DOSTEP(q1, b1, 0); q1 = LD2(sb + l + 5); b1 = LDB(sb + l + 5);
                    DOSTEP(q2, b2, 0); q2 = LD2(sb + l + 6); b2 = LDB(sb + l + 6);
                    DOSTEP(q3, b3, 0); q3 = LD2(sb + l + 7); b3 = LDB(sb + l + 7);
                }
            }
        } else if (c + 1 < NCH) {
            // ---------------- producers: fill chunk c+1 ----------------
            FILL(c + 1);
        }
        __syncthreads();
    }

    // final: -(log(alpha[S-1] + alpha[S-2])) on lane 63 of wave 0
    if (wave == 0 && lane == 63) {
        out[b] = -(logf(a3 + a4) + (float)Eacc * LN2F);
    }

#undef DOSTEP
#undef LD2
#undef LDB
#undef FILL
}

extern "C" void kernel_launch(void* const* d_in, const int* in_sizes, int n_in,
                              void* d_out, int out_size, void* d_ws, size_t ws_size,
                              hipStream_t stream) {
    (void)in_sizes; (void)n_in; (void)d_ws; (void)ws_size; (void)out_size;
    const int* y_true = (const int*)d_in[0];     // [B, L] int32
    const float* y_pred = (const float*)d_in[1]; // [B, T, V] float32
    float* out = (float*)d_out;                  // [B, 1] float32

    ctc_fwd_pc<<<CTC_B, 256, 0, stream>>>(y_true, y_pred, out);
}

// Round 4
// 63.678 us; speedup vs baseline: 3.7535x; 1.6178x over previous
//
#include <hip/hip_runtime.h>
#include <hip/hip_bf16.h>
#include <cstdint>

// CTC forward loss (keras ctc_batch_cost), B=64 T=1024 L=128 V=512.
// Probability-domain scaled forward algorithm, producer-consumer waves:
//   wave 0:   sequential scan; lane j owns states 4j..4j+3 (+ redundant 4j+4)
//   waves 1-3: gather p[t][labels] into LDS ring via global_load_lds
// All cross-lane ops are DPP (VALU): wave_shr:1 replaces shfl_up on the
// per-step chain; row_shr/row_bcast chain replaces the shfl_xor max-reduce.
// Renorm every 4 steps by power-of-2 (exact bookkeeping), scale application
// deferred one period (reduce latency hidden under the next 4 steps), scale
// target biased to 2^60 to keep the lagging operating point well in-range.

#define CTC_B 64
#define CTC_T 1024
#define CTC_L 128
#define CTC_V 512
#define BLANK (CTC_V - 1)
#define EPSF 1e-7f
#define LN2F 0.69314718055994530942f

#define CHUNK 32
#define NCH   (CTC_T / CHUNK)
#define SLOTW 128            // floats per step slot (label probs only)
#define BIASE 60             // renorm scale target = 2^BIASE

__device__ __forceinline__ void gld_lds(const float* g, float* l) {
    // per-lane global gather -> LDS at uniform base + lane*4
    __builtin_amdgcn_global_load_lds(
        (const __attribute__((address_space(1))) unsigned int*)g,
        (__attribute__((address_space(3))) unsigned int*)l,
        4, 0, 0);
}

// DPP move with old=0: wave_shr:1 (0x138) == shfl_up by 1 with 0 shifted in
template<int CTRL>
__device__ __forceinline__ float dpp_mov0(float v) {
    int r = __builtin_amdgcn_update_dpp(0, __float_as_int(v), CTRL, 0xf, 0xf, false);
    return __int_as_float(r);
}
// max(v, dpp(v)) — building block of the wave64 max reduction
template<int CTRL>
__device__ __forceinline__ float dpp_max(float v) {
    int r = __builtin_amdgcn_update_dpp(__float_as_int(v), __float_as_int(v),
                                        CTRL, 0xf, 0xf, false);
    return fmaxf(v, __int_as_float(r));
}

__global__ __launch_bounds__(256, 1)
void ctc_fwd_dpp(const int* __restrict__ y_true,
                 const float* __restrict__ y_pred,
                 float* __restrict__ out) {
    __shared__ __align__(16) float ring[2 * CHUNK * SLOTW];  // 32 KB
    __shared__ __align__(16) float blk[CTC_T];               // 4 KB (all blank probs)

    const int b = blockIdx.x;
    const int tid = threadIdx.x;
    const int wave = tid >> 6;
    const int lane = tid & 63;
    const float* __restrict__ yb = y_pred + (size_t)b * CTC_T * CTC_V;

    if (wave != 0) {
        // ---------------- producers: waves 1..3 ----------------
        const int labLo = y_true[b * CTC_L + lane];
        const int labHi = y_true[b * CTC_L + 64 + lane];
        // preload ALL blank probs: t = 64k + lane
        for (int k = wave - 1; k < CTC_T / 64; k += 3)
            gld_lds(yb + (size_t)(64 * k + lane) * CTC_V + BLANK, &blk[64 * k]);
        // fill chunk 0
        for (int l = wave - 1; l < CHUNK; l += 3) {
            const float* row = yb + (size_t)l * CTC_V;
            float* slot = &ring[l * SLOTW];
            gld_lds(row + labLo, slot);
            gld_lds(row + labHi, slot + 64);
        }
        __syncthreads();
        for (int c = 0; c < NCH; ++c) {
            if (c + 1 < NCH) {
                const int base = ((c + 1) & 1) * (CHUNK * SLOTW);
                const int t0n = (c + 1) * CHUNK;
                for (int l = wave - 1; l < CHUNK; l += 3) {
                    const float* row = yb + (size_t)(t0n + l) * CTC_V;
                    float* slot = &ring[base + l * SLOTW];
                    gld_lds(row + labLo, slot);
                    gld_lds(row + labHi, slot + 64);
                }
            }
            __syncthreads();
        }
        return;
    }

    // ---------------- consumer: wave 0 ----------------
    const int labA = y_true[b * CTC_L + 2 * lane];
    const int labB = y_true[b * CTC_L + 2 * lane + 1];
    const int labPrev = __shfl_up(labB, 1);
    const float msk1 = (labA != labPrev) ? 1.0f : 0.0f;  // state 4j+1 skip
    const float msk3 = (labB != labA) ? 1.0f : 0.0f;     // state 4j+3 skip

    float a0 = 0.0f, a1 = 0.0f, a2 = 0.0f, a3 = 0.0f, a4 = 0.0f;
    float curScale = 1.0f;
    int curE = 0, Eacc = 0;

    float2 qA0, qA1, qA2, qA3, qB0, qB1, qB2, qB3, qC0, qC1, qC2, qC3;
    float  bA0, bA1, bA2, bA3, bB0, bB1, bB2, bB3, bC0, bC1, bC2, bC3;

#define LD2(s_) (*(const float2*)&ring[sb + (s_) * SLOTW + 2 * lane])
#define BL(tt_) (blk[tt_])

#define LOADG(S, l_) do {                                                  \
        q##S##0 = LD2((l_));     q##S##1 = LD2((l_) + 1);                  \
        q##S##2 = LD2((l_) + 2); q##S##3 = LD2((l_) + 3);                  \
        b##S##0 = BL(t0 + (l_));     b##S##1 = BL(t0 + (l_) + 1);          \
        b##S##2 = BL(t0 + (l_) + 2); b##S##3 = BL(t0 + (l_) + 3);          \
    } while (0)

#define DOSTEP(qv, bv) do {                                                \
        const float pb_ = (bv) + EPSF;                                     \
        const float pA_ = (qv).x + EPSF;                                   \
        const float pB_ = (qv).y + EPSF;                                   \
        const float pm1_ = dpp_mov0<0x138>(a3);  /* wave_shr:1, lane0=0 */ \
        const float n0_ = (a0 + pm1_) * pb_;                               \
        const float n1_ = fmaf(msk1, pm1_, a0 + a1) * pA_;                 \
        const float n2_ = (a1 + a2) * pb_;                                 \
        const float n3_ = fmaf(msk3, a1, a2 + a3) * pB_;                   \
        const float n4_ = (a3 + a4) * pb_;                                 \
        a0 = n0_; a1 = n1_; a2 = n2_; a3 = n3_; a4 = n4_;                  \
    } while (0)

#define DORN() do {                                                        \
        a0 *= curScale; a1 *= curScale; a2 *= curScale;                    \
        a3 *= curScale; a4 *= curScale;                                    \
        Eacc += curE;                                                      \
        float m_ = fmaxf(fmaxf(fmaxf(a0, a1), fmaxf(a2, a3)), a4);         \
        m_ = dpp_max<0x111>(m_);  /* row_shr:1  */                         \
        m_ = dpp_max<0x112>(m_);  /* row_shr:2  */                         \
        m_ = dpp_max<0x114>(m_);  /* row_shr:4  */                         \
        m_ = dpp_max<0x118>(m_);  /* row_shr:8  */                         \
        m_ = dpp_max<0x142>(m_);  /* row_bcast:15 */                       \
        m_ = dpp_max<0x143>(m_);  /* row_bcast:31 */                       \
        const int mb_ = __builtin_amdgcn_readlane(__float_as_int(m_), 63); \
        const int e_ = (mb_ >> 23) & 255;                                  \
        int k_ = 127 + BIASE + 127 - e_;                                   \
        k_ = k_ > 254 ? 254 : (k_ < 1 ? 1 : k_);                           \
        curScale = __int_as_float((unsigned)k_ << 23);                     \
        curE = 127 - k_;                                                   \
    } while (0)

#define PROC4(S) do {                                                      \
        DOSTEP(q##S##0, b##S##0); DOSTEP(q##S##1, b##S##1);                \
        DOSTEP(q##S##2, b##S##2); DOSTEP(q##S##3, b##S##3);                \
    } while (0)
#define PROC4_RN(S) do {                                                   \
        DOSTEP(q##S##0, b##S##0); DORN();                                  \
        DOSTEP(q##S##1, b##S##1);                                          \
        DOSTEP(q##S##2, b##S##2); DOSTEP(q##S##3, b##S##3);                \
    } while (0)

    __syncthreads();  // matches producer prologue barrier

    for (int c = 0; c < NCH; ++c) {
        const int sb = (c & 1) * (CHUNK * SLOTW);
        const int t0 = c * CHUNK;
        if (c == 0) {
            // t=0 init: states 0 (blank) and 1 (lab[0]) only
            const float pb0 = BL(0) + EPSF;
            const float pl0 = ring[0] + EPSF;  // slot0 word0 = p[lab[0]]
            a0 = (lane == 0) ? pb0 : 0.0f;
            a1 = (lane == 0) ? pl0 : 0.0f;
            LOADG(A, 0); LOADG(B, 4); LOADG(C, 8);
            // steps t = 1..3
            DOSTEP(qA1, bA1); DOSTEP(qA2, bA2); DOSTEP(qA3, bA3);
            LOADG(A, 12);
            PROC4_RN(B); LOADG(B, 16);   // t = 4..7   (renorm at 4)
            PROC4_RN(C); LOADG(C, 20);   // t = 8..11
            PROC4_RN(A); LOADG(A, 24);   // t = 12..15
            PROC4_RN(B); LOADG(B, 28);   // t = 16..19
            PROC4_RN(C);                 // t = 20..23
            PROC4_RN(A);                 // t = 24..27
            PROC4_RN(B);                 // t = 28..31
        } else {
            LOADG(A, 0); LOADG(B, 4); LOADG(C, 8);
            PROC4_RN(A); LOADG(A, 12);
            PROC4_RN(B); LOADG(B, 16);
            PROC4_RN(C); LOADG(C, 20);
            PROC4_RN(A); LOADG(A, 24);
            PROC4_RN(B); LOADG(B, 28);
            PROC4_RN(C);
            PROC4_RN(A);
            PROC4_RN(B);
        }
        __syncthreads();
    }

    // final: -(log(alpha[S-1] + alpha[S-2])), states 255/256 live on lane 63
    if (lane == 63) {
        out[b] = -(logf(a3 + a4) + (float)Eacc * LN2F);
    }

#undef PROC4_RN
#undef PROC4
#undef DORN
#undef DOSTEP
#undef LOADG
#undef BL
#undef LD2
}

extern "C" void kernel_launch(void* const* d_in, const int* in_sizes, int n_in,
                              void* d_out, int out_size, void* d_ws, size_t ws_size,
                              hipStream_t stream) {
    (void)in_sizes; (void)n_in; (void)d_ws; (void)ws_size; (void)out_size;
    const int* y_true = (const int*)d_in[0];     // [B, L] int32
    const float* y_pred = (const float*)d_in[1]; // [B, T, V] float32
    float* out = (float*)d_out;                  // [B, 1] float32

    ctc_fwd_dpp<<<CTC_B, 256, 0, stream>>>(y_true, y_pred, out);
}